// Round 4
// baseline (47.723 us; speedup 1.0000x reference)
//
#include <hip/hip_runtime.h>
#include <hip/hip_bf16.h>
#include <math.h>

#define D_IN 512
#define NQ 4
#define QD 6
#define SPW 16              // samples per wave (one 16x16x32 MFMA tile chain)
#define WPB 4               // waves per block
#define SPB (SPW * WPB)     // 64 samples per block

typedef __attribute__((ext_vector_type(8))) short short8;   // 8 x bf16 bits
typedef __attribute__((ext_vector_type(4))) float f32x4;

__device__ __forceinline__ short bf16_of(float f) {
    return __bfloat16_as_short(__float2bfloat16(f));   // RNE
}
__device__ __forceinline__ short8 cvt8(float4 a, float4 b) {
    short8 r;
    r[0] = bf16_of(a.x); r[1] = bf16_of(a.y); r[2] = bf16_of(a.z); r[3] = bf16_of(a.w);
    r[4] = bf16_of(b.x); r[5] = bf16_of(b.y); r[6] = bf16_of(b.z); r[7] = bf16_of(b.w);
    return r;
}

// ---------------------------------------------------------------------------
// Fused kernel, MFMA GEMV edition.
// Phase 1: each wave computes pre_out for 16 samples via 16x16x32 bf16 MFMA
//   (A = x rows, B = W^T with 12 zero columns). No shuffles: the MFMA does the
//   cross-lane reduction; lanes with (lane&15)<4 hold D[sample][qubit] and
//   write tanh-scaled half-angles to LDS (4 ds_write_b32).
// Phase 2: threads 0..63 run the fully-unrolled 4-qubit statevector sim +
//   post-net, one sample each (unchanged from round 3).
// ---------------------------------------------------------------------------
__global__ __launch_bounds__(256, 4) void dqn_fused(
    const float* __restrict__ x,
    const float* __restrict__ pre_w,
    const float* __restrict__ pre_b,
    const float* __restrict__ q_params,
    const float* __restrict__ post_w,
    const float* __restrict__ post_b,
    float* __restrict__ out,
    int nsamp)
{
    __shared__ __align__(16) float ang[SPB][NQ];   // half-angles, 1 KB

    const int lane = threadIdx.x & 63;
    const int wv   = threadIdx.x >> 6;
    const int blk0 = blockIdx.x * SPB;
    const int s0   = blk0 + wv * SPW;

    // ---------------- phase 1: MFMA GEMV ----------------
    if (s0 < nsamp) {
        const int arow = lane & 15;     // A row (sample in tile) / C col (qubit)
        const int kgrp = lane >> 4;     // k-subgroup: elements 8*kgrp .. 8*kgrp+7

        // B fragments: B[k][col] = W^T[k][q] = pre_w[q][k]; cols 4..15 are zero.
        const bool act = arow < NQ;
        const float* wrow = pre_w + (size_t)(arow & 3) * D_IN + kgrp * 8;
        short8 B[16];
#pragma unroll
        for (int t = 0; t < 16; ++t) {
            float4 w0 = *reinterpret_cast<const float4*>(wrow + t * 32);
            float4 w1 = *reinterpret_cast<const float4*>(wrow + t * 32 + 4);
            if (!act) { w0 = make_float4(0.f, 0.f, 0.f, 0.f); w1 = w0; }
            B[t] = cvt8(w0, w1);
        }

        // A stream: lane reads x[s0+arow][8*kgrp + 32*t .. +7] per k-step.
        const float* xrow = x + (size_t)(s0 + arow) * D_IN + kgrp * 8;
        f32x4 acc = {0.f, 0.f, 0.f, 0.f};
#pragma unroll
        for (int t = 0; t < 16; ++t) {
            float4 p0 = *reinterpret_cast<const float4*>(xrow + t * 32);
            float4 p1 = *reinterpret_cast<const float4*>(xrow + t * 32 + 4);
            acc = __builtin_amdgcn_mfma_f32_16x16x32_bf16(cvt8(p0, p1), B[t], acc, 0, 0, 0);
        }

        // Epilogue: C[row=(kgrp*4+i)][col=arow] -> bias + tanh -> LDS.
        if (act) {
            const float bias = pre_b[arow];
#pragma unroll
            for (int i = 0; i < 4; ++i) {
                float t = acc[i] + bias;
                // tanh(t) = 1 - 2/(e^{2t}+1); __expf inf -> tanh -> 1 (ok)
                float e = __expf(2.0f * t);
                float th = 1.0f - 2.0f / (e + 1.0f);
                ang[wv * SPW + kgrp * 4 + i][arow] = th * 0.78539816339744831f;
            }
        }
    }
    __syncthreads();

    // ---------------- phase 2: sim + post-net (threads 0..63) ----------------
    if (threadIdx.x < SPB) {
        const int t = threadIdx.x;
        const int b = blk0 + t;
        if (b < nsamp) {
            float qc[QD][NQ], qs[QD][NQ];
#pragma unroll
            for (int k = 0; k < QD; ++k)
#pragma unroll
                for (int w = 0; w < NQ; ++w)
                    __sincosf(q_params[k * NQ + w] * 0.5f, &qs[k][w], &qc[k][w]);

            float4 ha = *reinterpret_cast<const float4*>(&ang[t][0]);
            float s0_, c0_, s1_, c1_, s2_, c2_, s3_, c3_;
            __sincosf(ha.x, &s0_, &c0_);
            __sincosf(ha.y, &s1_, &c1_);
            __sincosf(ha.z, &s2_, &c2_);
            __sincosf(ha.w, &s3_, &c3_);

            const float r2 = 0.70710678118654752f;
            float A0[2] = {(c0_ - s0_) * r2, (c0_ + s0_) * r2};
            float A1[2] = {(c1_ - s1_) * r2, (c1_ + s1_) * r2};
            float A2[2] = {(c2_ - s2_) * r2, (c2_ + s2_) * r2};
            float A3[2] = {(c3_ - s3_) * r2, (c3_ + s3_) * r2};

            float u[4], v[4], st[16];
#pragma unroll
            for (int i = 0; i < 4; ++i) { u[i] = A0[i >> 1] * A1[i & 1]; v[i] = A2[i >> 1] * A3[i & 1]; }
#pragma unroll
            for (int i = 0; i < 16; ++i) st[i] = u[i >> 2] * v[i & 3];

#pragma unroll
            for (int k = 0; k < QD; ++k) {
                // CNOT(0,1): b0=1 -> swap b1 (compile-time reg permutation)
#pragma unroll
                for (int j = 0; j < 4; ++j) { float tt = st[8 + j]; st[8 + j] = st[12 + j]; st[12 + j] = tt; }
                // CNOT(2,3): b2=1 -> swap b3
#pragma unroll
                for (int j = 0; j < 4; ++j) { float tt = st[4 * j + 2]; st[4 * j + 2] = st[4 * j + 3]; st[4 * j + 3] = tt; }
                // CNOT(1,2): b1=1 -> swap b2
#pragma unroll
                for (int j = 0; j < 2; ++j)
#pragma unroll
                    for (int d = 0; d < 2; ++d) {
                        const int i0 = j * 8 + 4 + d;
                        float tt = st[i0]; st[i0] = st[i0 + 2]; st[i0 + 2] = tt;
                    }
                // RY on each wire
#pragma unroll
                for (int w = 0; w < NQ; ++w) {
                    const int m = 8 >> w;
                    const float c = qc[k][w], s = qs[k][w];
#pragma unroll
                    for (int i = 0; i < 16; ++i) {
                        if ((i & m) == 0) {
                            float x0 = st[i], x1 = st[i | m];
                            st[i]     = c * x0 - s * x1;
                            st[i | m] = s * x0 + c * x1;
                        }
                    }
                }
            }

            float e0 = 0.f, e1 = 0.f, e2 = 0.f, e3 = 0.f;
#pragma unroll
            for (int i = 0; i < 16; ++i) {
                float p = st[i] * st[i];
                e0 += (i & 8) ? -p : p;
                e1 += (i & 4) ? -p : p;
                e2 += (i & 2) ? -p : p;
                e3 += (i & 1) ? -p : p;
            }

            float r[10];
#pragma unroll
            for (int c = 0; c < 10; ++c) {
                r[c] = post_b[c] + e0 * post_w[c * 4 + 0] + e1 * post_w[c * 4 + 1]
                     + e2 * post_w[c * 4 + 2] + e3 * post_w[c * 4 + 3];
            }
            float2* orow = reinterpret_cast<float2*>(out + (size_t)b * 10);
#pragma unroll
            for (int c = 0; c < 5; ++c)
                orow[c] = make_float2(r[2 * c], r[2 * c + 1]);
        }
    }
}

extern "C" void kernel_launch(void* const* d_in, const int* in_sizes, int n_in,
                              void* d_out, int out_size, void* d_ws, size_t ws_size,
                              hipStream_t stream)
{
    const float* x      = (const float*)d_in[0];
    const float* pre_w  = (const float*)d_in[1];
    const float* pre_b  = (const float*)d_in[2];
    const float* q_par  = (const float*)d_in[3];
    const float* post_w = (const float*)d_in[4];
    const float* post_b = (const float*)d_in[5];
    float* out = (float*)d_out;

    const int nsamp = in_sizes[0] / D_IN;              // 65536
    dim3 blk(256);
    dim3 grid((nsamp + SPB - 1) / SPB);                // 1024 blocks
    dqn_fused<<<grid, blk, 0, stream>>>(x, pre_w, pre_b, q_par, post_w, post_b, out, nsamp);
}

// Round 6
// 29.851 us; speedup vs baseline: 1.5987x; 1.5987x over previous
//
#include <hip/hip_runtime.h>
#include <math.h>

#define D_IN 512
#define NQ 4
#define QD 6
#define SPW 8               // samples per wave (GEMV phase)
#define WPB 4               // waves per block
#define SPB (SPW * WPB)     // 32 samples per block

typedef __attribute__((ext_vector_type(4))) float fvec4;   // native vector for nt-load

__device__ __forceinline__ float dot4v(fvec4 a, float4 b) {
    return a.x * b.x + a.y * b.y + a.z * b.z + a.w * b.w;
}

// ---------------------------------------------------------------------------
// Fused kernel (round-3 structure, occupancy edition).
// Phase 1 (all 4 waves): pre-net GEMV + tanh. Each wave handles 8 samples in
//   2 chunks of 4 (8 nontemporal float4 loads in flight per chunk), weights
//   in registers, 10-shuffle fold -> lane l holds dot(qubit=l&3); lanes 0..3
//   write half-angles to LDS.
// Phase 2 (threads 0..SPB-1): fully-unrolled 4-qubit statevector sim +
//   post-net, one sample per thread. q_params sincos per-layer to keep VGPR
//   low enough for 6 waves/SIMD (__launch_bounds__(256,6)).
// ---------------------------------------------------------------------------
__global__ __launch_bounds__(256, 6) void dqn_fused(
    const float* __restrict__ x,
    const float* __restrict__ pre_w,
    const float* __restrict__ pre_b,
    const float* __restrict__ q_params,
    const float* __restrict__ post_w,
    const float* __restrict__ post_b,
    float* __restrict__ out,
    int nsamp)
{
    __shared__ __align__(16) float ang[SPB][NQ];   // half-angles, 512 B

    const int lane = threadIdx.x & 63;
    const int wv   = threadIdx.x >> 6;
    const int blk0 = blockIdx.x * SPB;

    // ---------------- phase 1: GEMV ----------------
    {
        const int s0 = blk0 + wv * SPW;
        if (s0 < nsamp) {
            const fvec4* xr = reinterpret_cast<const fvec4*>(x);
            const float4* wr = reinterpret_cast<const float4*>(pre_w);

            float4 wA[4], wB[4];
#pragma unroll
            for (int q = 0; q < 4; ++q) {
                wA[q] = wr[q * (D_IN / 4) + lane];
                wB[q] = wr[q * (D_IN / 4) + 64 + lane];
            }
            const float bias = pre_b[lane & 3];

#pragma unroll
            for (int ch = 0; ch < SPW / 4; ++ch) {
                // batch-issue 8 nontemporal float4 loads (4 samples)
                fvec4 xa[4], xb[4];
#pragma unroll
                for (int j = 0; j < 4; ++j) {
                    const size_t row = (size_t)(s0 + ch * 4 + j) * (D_IN / 4);
                    xa[j] = __builtin_nontemporal_load(xr + row + lane);
                    xb[j] = __builtin_nontemporal_load(xr + row + 64 + lane);
                }
#pragma unroll
                for (int j = 0; j < 4; ++j) {
                    float a0 = dot4v(xa[j], wA[0]) + dot4v(xb[j], wB[0]);
                    float a1 = dot4v(xa[j], wA[1]) + dot4v(xb[j], wB[1]);
                    float a2 = dot4v(xa[j], wA[2]) + dot4v(xb[j], wB[2]);
                    float a3 = dot4v(xa[j], wA[3]) + dot4v(xb[j], wB[3]);

                    // fold 4 accumulators -> lane carries qubit (lane&3)
                    a0 += __shfl_xor(a0, 1, 64);
                    a1 += __shfl_xor(a1, 1, 64);
                    a2 += __shfl_xor(a2, 1, 64);
                    a3 += __shfl_xor(a3, 1, 64);
                    float b0 = (lane & 1) ? a1 : a0;
                    float b1 = (lane & 1) ? a3 : a2;
                    b0 += __shfl_xor(b0, 2, 64);
                    b1 += __shfl_xor(b1, 2, 64);
                    float c = (lane & 2) ? b1 : b0;
                    c += __shfl_xor(c, 4, 64);
                    c += __shfl_xor(c, 8, 64);
                    c += __shfl_xor(c, 16, 64);
                    c += __shfl_xor(c, 32, 64);

                    float t = c + bias;
                    // tanh(t) = 1 - 2/(e^{2t}+1); __expf inf -> tanh -> 1 (ok)
                    float e = __expf(2.0f * t);
                    float th = 1.0f - 2.0f / (e + 1.0f);
                    if (lane < 4)
                        ang[wv * SPW + ch * 4 + j][lane] = th * 0.78539816339744831f;
                }
            }
        }
    }
    __syncthreads();

    // ---------------- phase 2: sim + post-net (threads 0..SPB-1) ----------------
    if (threadIdx.x < SPB) {
        const int t = threadIdx.x;
        const int b = blk0 + t;
        if (b < nsamp) {
            float4 ha = *reinterpret_cast<const float4*>(&ang[t][0]);
            float s0_, c0_, s1_, c1_, s2_, c2_, s3_, c3_;
            __sincosf(ha.x, &s0_, &c0_);
            __sincosf(ha.y, &s1_, &c1_);
            __sincosf(ha.z, &s2_, &c2_);
            __sincosf(ha.w, &s3_, &c3_);

            const float r2 = 0.70710678118654752f;
            float A0[2] = {(c0_ - s0_) * r2, (c0_ + s0_) * r2};
            float A1[2] = {(c1_ - s1_) * r2, (c1_ + s1_) * r2};
            float A2[2] = {(c2_ - s2_) * r2, (c2_ + s2_) * r2};
            float A3[2] = {(c3_ - s3_) * r2, (c3_ + s3_) * r2};

            float u[4], v[4], st[16];
#pragma unroll
            for (int i = 0; i < 4; ++i) { u[i] = A0[i >> 1] * A1[i & 1]; v[i] = A2[i >> 1] * A3[i & 1]; }
#pragma unroll
            for (int i = 0; i < 16; ++i) st[i] = u[i >> 2] * v[i & 3];

#pragma unroll
            for (int k = 0; k < QD; ++k) {
                // CNOT(0,1): b0=1 -> swap b1 (compile-time reg permutation)
#pragma unroll
                for (int j = 0; j < 4; ++j) { float tt = st[8 + j]; st[8 + j] = st[12 + j]; st[12 + j] = tt; }
                // CNOT(2,3): b2=1 -> swap b3
#pragma unroll
                for (int j = 0; j < 4; ++j) { float tt = st[4 * j + 2]; st[4 * j + 2] = st[4 * j + 3]; st[4 * j + 3] = tt; }
                // CNOT(1,2): b1=1 -> swap b2
#pragma unroll
                for (int j = 0; j < 2; ++j)
#pragma unroll
                    for (int d = 0; d < 2; ++d) {
                        const int i0 = j * 8 + 4 + d;
                        float tt = st[i0]; st[i0] = st[i0 + 2]; st[i0 + 2] = tt;
                    }
                // RY on each wire (per-layer sincos: keeps VGPR low)
                float qc[NQ], qs[NQ];
#pragma unroll
                for (int w = 0; w < NQ; ++w)
                    __sincosf(q_params[k * NQ + w] * 0.5f, &qs[w], &qc[w]);
#pragma unroll
                for (int w = 0; w < NQ; ++w) {
                    const int m = 8 >> w;
                    const float c = qc[w], s = qs[w];
#pragma unroll
                    for (int i = 0; i < 16; ++i) {
                        if ((i & m) == 0) {
                            float x0 = st[i], x1 = st[i | m];
                            st[i]     = c * x0 - s * x1;
                            st[i | m] = s * x0 + c * x1;
                        }
                    }
                }
            }

            float e0 = 0.f, e1 = 0.f, e2 = 0.f, e3 = 0.f;
#pragma unroll
            for (int i = 0; i < 16; ++i) {
                float p = st[i] * st[i];
                e0 += (i & 8) ? -p : p;
                e1 += (i & 4) ? -p : p;
                e2 += (i & 2) ? -p : p;
                e3 += (i & 1) ? -p : p;
            }

            float r[10];
#pragma unroll
            for (int c = 0; c < 10; ++c) {
                r[c] = post_b[c] + e0 * post_w[c * 4 + 0] + e1 * post_w[c * 4 + 1]
                     + e2 * post_w[c * 4 + 2] + e3 * post_w[c * 4 + 3];
            }
            float2* orow = reinterpret_cast<float2*>(out + (size_t)b * 10);
#pragma unroll
            for (int c = 0; c < 5; ++c)
                orow[c] = make_float2(r[2 * c], r[2 * c + 1]);
        }
    }
}

extern "C" void kernel_launch(void* const* d_in, const int* in_sizes, int n_in,
                              void* d_out, int out_size, void* d_ws, size_t ws_size,
                              hipStream_t stream)
{
    const float* x      = (const float*)d_in[0];
    const float* pre_w  = (const float*)d_in[1];
    const float* pre_b  = (const float*)d_in[2];
    const float* q_par  = (const float*)d_in[3];
    const float* post_w = (const float*)d_in[4];
    const float* post_b = (const float*)d_in[5];
    float* out = (float*)d_out;

    const int nsamp = in_sizes[0] / D_IN;              // 65536
    dim3 blk(256);
    dim3 grid((nsamp + SPB - 1) / SPB);                // 2048 blocks
    dqn_fused<<<grid, blk, 0, stream>>>(x, pre_w, pre_b, q_par, post_w, post_b, out, nsamp);
}